// Round 3
// baseline (122.973 us; speedup 1.0000x reference)
//
#include <hip/hip_runtime.h>
#include <math.h>

#define BATCH 8192
#define DIM   2048

// One wave per batch row. y is staged through LDS so global loads are
// lane-contiguous (coalesced 1KB/instr); an XOR bank swizzle keeps both the
// staging writes and the chunk-ordered reads at the inherent 1KB/instr LDS
// serialization. Since y is binary, 8 timesteps fold into one matmul against
// a 256-entry LDS table of 8-step products (stride padded to 12 floats so
// reads are 3x ds_read_b128). The t=0 start-vector step is handled
// algebraically: the full-row product P = Prod_t M_{y_t} is uniform across
// lanes, and log_prob = log(v^T P 1) with v solving T^T v = pi
// (v^T = alpha0^T M_{y0}^{-1} = pi^T T^{-1}, independent of y0).
__global__ __launch_bounds__(256, 4)
void hmm_fwd(const int* __restrict__ y,
             const float* __restrict__ tp,
             const float* __restrict__ ep,
             const float* __restrict__ sp,
             float* __restrict__ row_lp,
             float* __restrict__ out_atomic)
{
    __shared__ __align__(16) float t4[16 * 12];
    __shared__ __align__(16) float t8[256 * 12];
    __shared__ __align__(16) int   ystage[4][DIM];

    const int tid  = threadIdx.x;
    const int lane = tid & 63;
    const int wid  = tid >> 6;
    const int b    = blockIdx.x * 4 + wid;

    // ---- issue coalesced global loads early (latency overlaps table build)
    const int* __restrict__ yb = y + (size_t)b * DIM;
    int4 ld[8];
    #pragma unroll
    for (int g = 0; g < 8; ++g)
        ld[g] = *reinterpret_cast<const int4*>(yb + g * 256 + lane * 4);

    // ---- normalized parameters (uniform per thread) ----
    float T[3][3], E[3][2], pi[3];
    #pragma unroll
    for (int i = 0; i < 3; ++i) {
        float a0 = tp[i*3+0], a1 = tp[i*3+1], a2 = tp[i*3+2];
        float mx = fmaxf(a0, fmaxf(a1, a2));
        float e0 = __expf(a0-mx), e1 = __expf(a1-mx), e2 = __expf(a2-mx);
        float inv = 1.0f / (e0+e1+e2);
        T[i][0] = e0*inv; T[i][1] = e1*inv; T[i][2] = e2*inv;
    }
    #pragma unroll
    for (int s = 0; s < 3; ++s) {
        float a0 = ep[s*2+0], a1 = ep[s*2+1];
        float mx = fmaxf(a0, a1);
        float e0 = __expf(a0-mx), e1 = __expf(a1-mx);
        float inv = 1.0f / (e0+e1);
        E[s][0] = e0*inv; E[s][1] = e1*inv;
    }
    {
        float a0 = sp[0], a1 = sp[1], a2 = sp[2];
        float mx = fmaxf(a0, fmaxf(a1, a2));
        float e0 = __expf(a0-mx), e1 = __expf(a1-mx), e2 = __expf(a2-mx);
        float inv = 1.0f / (e0+e1+e2);
        pi[0] = e0*inv; pi[1] = e1*inv; pi[2] = e2*inv;
    }

    // v solves T^T v = pi  (adjugate solve)
    float v0, v1, v2;
    {
        float c00 =  (T[1][1]*T[2][2] - T[1][2]*T[2][1]);
        float c01 = -(T[1][0]*T[2][2] - T[1][2]*T[2][0]);
        float c02 =  (T[1][0]*T[2][1] - T[1][1]*T[2][0]);
        float c10 = -(T[0][1]*T[2][2] - T[0][2]*T[2][1]);
        float c11 =  (T[0][0]*T[2][2] - T[0][2]*T[2][0]);
        float c12 = -(T[0][0]*T[2][1] - T[0][1]*T[2][0]);
        float c20 =  (T[0][1]*T[1][2] - T[0][2]*T[1][1]);
        float c21 = -(T[0][0]*T[1][2] - T[0][2]*T[1][0]);
        float c22 =  (T[0][0]*T[1][1] - T[0][1]*T[1][0]);
        float det = T[0][0]*c00 + T[0][1]*c01 + T[0][2]*c02;
        float invd = 1.0f / det;
        v0 = (pi[0]*c00 + pi[1]*c01 + pi[2]*c02) * invd;
        v1 = (pi[0]*c10 + pi[1]*c11 + pi[2]*c12) * invd;
        v2 = (pi[0]*c20 + pi[1]*c21 + pi[2]*c22) * invd;
    }

    // per-step matrices M_y[k*3+j] = T[k][j] * E[j][y]
    float M0[9], M1[9];
    #pragma unroll
    for (int k = 0; k < 3; ++k)
        #pragma unroll
        for (int j = 0; j < 3; ++j) {
            M0[k*3+j] = T[k][j] * E[j][0];
            M1[k*3+j] = T[k][j] * E[j][1];
        }

    // ---- build 4-step table (16 entries), then 8-step table (256) ----
    if (tid < 16) {
        int code = tid;
        float A[9];
        const float* F0 = (code & 1) ? M1 : M0;
        #pragma unroll
        for (int e = 0; e < 9; ++e) A[e] = F0[e];
        code >>= 1;
        for (int s = 1; s < 4; ++s) {
            const float* F = (code & 1) ? M1 : M0;
            code >>= 1;
            float Z[9];
            #pragma unroll
            for (int i = 0; i < 3; ++i)
                #pragma unroll
                for (int j = 0; j < 3; ++j)
                    Z[i*3+j] = fmaf(A[i*3+0], F[0*3+j],
                               fmaf(A[i*3+1], F[1*3+j], A[i*3+2]*F[2*3+j]));
            #pragma unroll
            for (int e = 0; e < 9; ++e) A[e] = Z[e];
        }
        #pragma unroll
        for (int e = 0; e < 9; ++e) t4[tid*12 + e] = A[e];
        t4[tid*12 +  9] = 0.0f; t4[tid*12 + 10] = 0.0f; t4[tid*12 + 11] = 0.0f;
    }
    __syncthreads();
    {
        const float* A = &t4[(tid & 15) * 12];
        const float* B = &t4[(tid >> 4) * 12];
        float Z[9];
        #pragma unroll
        for (int i = 0; i < 3; ++i)
            #pragma unroll
            for (int j = 0; j < 3; ++j)
                Z[i*3+j] = fmaf(A[i*3+0], B[0*3+j],
                           fmaf(A[i*3+1], B[1*3+j], A[i*3+2]*B[2*3+j]));
        #pragma unroll
        for (int e = 0; e < 9; ++e) t8[tid*12 + e] = Z[e];
        t8[tid*12 +  9] = 0.0f; t8[tid*12 + 10] = 0.0f; t8[tid*12 + 11] = 0.0f;
    }

    // ---- stage y into LDS, bank-swizzled ----
    // logical (chunk L, int4 m) lives at element offset L*32 + (m^(L&7))*4
    #pragma unroll
    for (int g = 0; g < 8; ++g) {
        int Lp = 8*g + (lane >> 3);
        int m  = lane & 7;
        int off = Lp*32 + ((m ^ (Lp & 7)) * 4);
        *reinterpret_cast<int4*>(&ystage[wid][off]) = ld[g];
    }
    __syncthreads();

    int4 q[8];
    #pragma unroll
    for (int k = 0; k < 8; ++k) {
        int off = lane*32 + ((k ^ (lane & 7)) * 4);
        q[k] = *reinterpret_cast<const int4*>(&ystage[wid][off]);
    }

    // ---- 4 groups of 8 timesteps ----
    float R[9] = {1.f,0.f,0.f, 0.f,1.f,0.f, 0.f,0.f,1.f};
    float lsc = 0.0f;

    #pragma unroll
    for (int j = 0; j < 4; ++j) {
        int4 a = q[2*j], c = q[2*j+1];
        int idx = a.x + (a.y<<1) + (a.z<<2) + (a.w<<3)
                + (c.x<<4) + (c.y<<5) + (c.z<<6) + (c.w<<7);
        const float4* G4 = reinterpret_cast<const float4*>(&t8[idx * 12]);
        float4 p0 = G4[0], p1 = G4[1], p2 = G4[2];
        float g0 = p0.x, g1 = p0.y, g2 = p0.z,
              g3 = p0.w, g4 = p1.x, g5 = p1.y,
              g6 = p1.z, g7 = p1.w, g8 = p2.x;
        float nR[9];
        #pragma unroll
        for (int i = 0; i < 3; ++i) {
            nR[i*3+0] = fmaf(R[i*3+0], g0, fmaf(R[i*3+1], g3, R[i*3+2]*g6));
            nR[i*3+1] = fmaf(R[i*3+0], g1, fmaf(R[i*3+1], g4, R[i*3+2]*g7));
            nR[i*3+2] = fmaf(R[i*3+0], g2, fmaf(R[i*3+1], g5, R[i*3+2]*g8));
        }
        #pragma unroll
        for (int e = 0; e < 9; ++e) R[e] = nR[e];

        if (j == 1 || j == 3) {
            float m = R[0];
            #pragma unroll
            for (int e = 1; e < 9; ++e) m = fmaxf(m, R[e]);
            lsc += __logf(m);
            float inv = 1.0f / m;
            #pragma unroll
            for (int e = 0; e < 9; ++e) R[e] *= inv;
        }
    }

    // ---- ordered wave reduction: R_lane = R_lane @ R_{lane+offset} ----
    #pragma unroll
    for (int o = 1; o < 64; o <<= 1) {
        float S[9];
        #pragma unroll
        for (int e = 0; e < 9; ++e) S[e] = __shfl_down(R[e], o, 64);
        float osc = __shfl_down(lsc, o, 64);
        float nR[9];
        #pragma unroll
        for (int i = 0; i < 3; ++i)
            #pragma unroll
            for (int j = 0; j < 3; ++j)
                nR[i*3+j] = fmaf(R[i*3+0], S[0*3+j],
                            fmaf(R[i*3+1], S[1*3+j], R[i*3+2]*S[2*3+j]));
        #pragma unroll
        for (int e = 0; e < 9; ++e) R[e] = nR[e];
        lsc += osc;
    }

    if (lane == 0) {
        float r0 = R[0] + R[1] + R[2];
        float r1 = R[3] + R[4] + R[5];
        float r2 = R[6] + R[7] + R[8];
        float p  = fmaf(v0, r0, fmaf(v1, r1, v2 * r2));
        float lp = __logf(p) + lsc;
        if (row_lp) row_lp[b] = lp;
        else        atomicAdd(out_atomic, lp * (1.0f / BATCH));
    }
}

__global__ void reduce_mean(const float* __restrict__ row, float* __restrict__ out)
{
    float s = 0.0f;
    for (int i = threadIdx.x; i < BATCH; i += 1024) s += row[i];
    #pragma unroll
    for (int o = 32; o > 0; o >>= 1) s += __shfl_down(s, o, 64);
    __shared__ float sm[16];
    int w = threadIdx.x >> 6;
    if ((threadIdx.x & 63) == 0) sm[w] = s;
    __syncthreads();
    if (threadIdx.x == 0) {
        float t = 0.0f;
        #pragma unroll
        for (int i = 0; i < 16; ++i) t += sm[i];
        out[0] = t * (1.0f / BATCH);
    }
}

extern "C" void kernel_launch(void* const* d_in, const int* in_sizes, int n_in,
                              void* d_out, int out_size, void* d_ws, size_t ws_size,
                              hipStream_t stream)
{
    const int*   y  = (const int*)d_in[0];
    const float* tp = (const float*)d_in[1];
    const float* ep = (const float*)d_in[2];
    const float* sp = (const float*)d_in[3];
    float* out = (float*)d_out;

    const bool use_ws = (ws_size >= BATCH * sizeof(float));
    if (use_ws) {
        float* row = (float*)d_ws;
        hmm_fwd<<<BATCH/4, 256, 0, stream>>>(y, tp, ep, sp, row, nullptr);
        reduce_mean<<<1, 1024, 0, stream>>>(row, out);
    } else {
        hipMemsetAsync(out, 0, sizeof(float), stream);
        hmm_fwd<<<BATCH/4, 256, 0, stream>>>(y, tp, ep, sp, nullptr, out);
    }
}

// Round 4
// 104.273 us; speedup vs baseline: 1.1793x; 1.1793x over previous
//
#include <hip/hip_runtime.h>
#include <math.h>

#define BATCH 8192
#define DIM   2048

// One wave per batch row. Each global int4 load of y is IMMEDIATELY stored
// (XOR-bank-swizzled) into this wave's private LDS staging row, so the load
// registers have no live range across the table-build section (round 3
// held them in an array across ~80 insts -> 64MB scratch spill, WRITE_SIZE
// counter caught it). 8 timesteps fold into one 3x3 matmul against a
// 256-entry LDS table of 8-step products (12-float stride -> ds_read_b128).
// t=0 is handled algebraically: log_prob = log(v^T P 1) with T^T v = pi,
// where P = Prod_{t>=0} M_{y_t} is the uniform full-row product.
__global__ __launch_bounds__(256, 4)
void hmm_fwd(const int* __restrict__ y,
             const float* __restrict__ tp,
             const float* __restrict__ ep,
             const float* __restrict__ sp,
             float* __restrict__ row_lp,
             float* __restrict__ out_atomic)
{
    __shared__ __align__(16) float t4[16 * 12];
    __shared__ __align__(16) float t8[256 * 12];
    __shared__ __align__(16) int   ystage[4][DIM];

    const int tid  = threadIdx.x;
    const int lane = tid & 63;
    const int wid  = tid >> 6;
    const int b    = blockIdx.x * 4 + wid;

    // ---- coalesced load -> immediate swizzled LDS store (short liveness) --
    // logical (chunk L, int4 m) lives at element offset L*32 + (m^(L&7))*4
    const int* __restrict__ yb = y + (size_t)b * DIM;
    #pragma unroll
    for (int g = 0; g < 8; ++g) {
        int4 v = *reinterpret_cast<const int4*>(yb + g * 256 + lane * 4);
        int Lp = 8*g + (lane >> 3);
        int m  = lane & 7;
        int off = Lp*32 + ((m ^ (Lp & 7)) * 4);
        *reinterpret_cast<int4*>(&ystage[wid][off]) = v;
    }

    // ---- normalized parameters (uniform per thread) ----
    float T[3][3], E[3][2], pi[3];
    #pragma unroll
    for (int i = 0; i < 3; ++i) {
        float a0 = tp[i*3+0], a1 = tp[i*3+1], a2 = tp[i*3+2];
        float mx = fmaxf(a0, fmaxf(a1, a2));
        float e0 = __expf(a0-mx), e1 = __expf(a1-mx), e2 = __expf(a2-mx);
        float inv = 1.0f / (e0+e1+e2);
        T[i][0] = e0*inv; T[i][1] = e1*inv; T[i][2] = e2*inv;
    }
    #pragma unroll
    for (int s = 0; s < 3; ++s) {
        float a0 = ep[s*2+0], a1 = ep[s*2+1];
        float mx = fmaxf(a0, a1);
        float e0 = __expf(a0-mx), e1 = __expf(a1-mx);
        float inv = 1.0f / (e0+e1);
        E[s][0] = e0*inv; E[s][1] = e1*inv;
    }
    {
        float a0 = sp[0], a1 = sp[1], a2 = sp[2];
        float mx = fmaxf(a0, fmaxf(a1, a2));
        float e0 = __expf(a0-mx), e1 = __expf(a1-mx), e2 = __expf(a2-mx);
        float inv = 1.0f / (e0+e1+e2);
        pi[0] = e0*inv; pi[1] = e1*inv; pi[2] = e2*inv;
    }

    // v solves T^T v = pi (adjugate solve); folds start vector + t=0 step
    float v0, v1, v2;
    {
        float c00 =  (T[1][1]*T[2][2] - T[1][2]*T[2][1]);
        float c01 = -(T[1][0]*T[2][2] - T[1][2]*T[2][0]);
        float c02 =  (T[1][0]*T[2][1] - T[1][1]*T[2][0]);
        float c10 = -(T[0][1]*T[2][2] - T[0][2]*T[2][1]);
        float c11 =  (T[0][0]*T[2][2] - T[0][2]*T[2][0]);
        float c12 = -(T[0][0]*T[2][1] - T[0][1]*T[2][0]);
        float c20 =  (T[0][1]*T[1][2] - T[0][2]*T[1][1]);
        float c21 = -(T[0][0]*T[1][2] - T[0][2]*T[1][0]);
        float c22 =  (T[0][0]*T[1][1] - T[0][1]*T[1][0]);
        float det = T[0][0]*c00 + T[0][1]*c01 + T[0][2]*c02;
        float invd = 1.0f / det;
        v0 = (pi[0]*c00 + pi[1]*c01 + pi[2]*c02) * invd;
        v1 = (pi[0]*c10 + pi[1]*c11 + pi[2]*c12) * invd;
        v2 = (pi[0]*c20 + pi[1]*c21 + pi[2]*c22) * invd;
    }

    // per-step matrices M_y[k*3+j] = T[k][j] * E[j][y]
    float M0[9], M1[9];
    #pragma unroll
    for (int k = 0; k < 3; ++k)
        #pragma unroll
        for (int j = 0; j < 3; ++j) {
            M0[k*3+j] = T[k][j] * E[j][0];
            M1[k*3+j] = T[k][j] * E[j][1];
        }

    // ---- build 4-step table (16 entries), then 8-step table (256) ----
    if (tid < 16) {
        int code = tid;
        float A[9];
        const float* F0 = (code & 1) ? M1 : M0;
        #pragma unroll
        for (int e = 0; e < 9; ++e) A[e] = F0[e];
        code >>= 1;
        for (int s = 1; s < 4; ++s) {
            const float* F = (code & 1) ? M1 : M0;
            code >>= 1;
            float Z[9];
            #pragma unroll
            for (int i = 0; i < 3; ++i)
                #pragma unroll
                for (int j = 0; j < 3; ++j)
                    Z[i*3+j] = fmaf(A[i*3+0], F[0*3+j],
                               fmaf(A[i*3+1], F[1*3+j], A[i*3+2]*F[2*3+j]));
            #pragma unroll
            for (int e = 0; e < 9; ++e) A[e] = Z[e];
        }
        #pragma unroll
        for (int e = 0; e < 9; ++e) t4[tid*12 + e] = A[e];
    }
    __syncthreads();
    {
        const float* A = &t4[(tid & 15) * 12];
        const float* B = &t4[(tid >> 4) * 12];
        float Z[9];
        #pragma unroll
        for (int i = 0; i < 3; ++i)
            #pragma unroll
            for (int j = 0; j < 3; ++j)
                Z[i*3+j] = fmaf(A[i*3+0], B[0*3+j],
                           fmaf(A[i*3+1], B[1*3+j], A[i*3+2]*B[2*3+j]));
        #pragma unroll
        for (int e = 0; e < 9; ++e) t8[tid*12 + e] = Z[e];
    }
    __syncthreads();

    // ---- 4 groups of 8 timesteps; q read per group (low reg pressure) ----
    float R[9] = {1.f,0.f,0.f, 0.f,1.f,0.f, 0.f,0.f,1.f};
    float lsc = 0.0f;
    const int lx = lane & 7;
    const int* __restrict__ yrow = &ystage[wid][lane * 32];

    #pragma unroll
    for (int j = 0; j < 4; ++j) {
        int4 a = *reinterpret_cast<const int4*>(yrow + (((2*j)   ^ lx) * 4));
        int4 c = *reinterpret_cast<const int4*>(yrow + (((2*j+1) ^ lx) * 4));
        int idx = a.x + (a.y<<1) + (a.z<<2) + (a.w<<3)
                + (c.x<<4) + (c.y<<5) + (c.z<<6) + (c.w<<7);
        const float4* G4 = reinterpret_cast<const float4*>(&t8[idx * 12]);
        float4 p0 = G4[0], p1 = G4[1], p2 = G4[2];
        float g0 = p0.x, g1 = p0.y, g2 = p0.z,
              g3 = p0.w, g4 = p1.x, g5 = p1.y,
              g6 = p1.z, g7 = p1.w, g8 = p2.x;
        float nR[9];
        #pragma unroll
        for (int i = 0; i < 3; ++i) {
            nR[i*3+0] = fmaf(R[i*3+0], g0, fmaf(R[i*3+1], g3, R[i*3+2]*g6));
            nR[i*3+1] = fmaf(R[i*3+0], g1, fmaf(R[i*3+1], g4, R[i*3+2]*g7));
            nR[i*3+2] = fmaf(R[i*3+0], g2, fmaf(R[i*3+1], g5, R[i*3+2]*g8));
        }
        #pragma unroll
        for (int e = 0; e < 9; ++e) R[e] = nR[e];

        if (j == 1 || j == 3) {
            float m = R[0];
            #pragma unroll
            for (int e = 1; e < 9; ++e) m = fmaxf(m, R[e]);
            lsc += __logf(m);
            float inv = 1.0f / m;
            #pragma unroll
            for (int e = 0; e < 9; ++e) R[e] *= inv;
        }
    }

    // ---- ordered wave reduction: R_lane = R_lane @ R_{lane+offset} ----
    #pragma unroll
    for (int o = 1; o < 64; o <<= 1) {
        float S[9];
        #pragma unroll
        for (int e = 0; e < 9; ++e) S[e] = __shfl_down(R[e], o, 64);
        float osc = __shfl_down(lsc, o, 64);
        float nR[9];
        #pragma unroll
        for (int i = 0; i < 3; ++i)
            #pragma unroll
            for (int j = 0; j < 3; ++j)
                nR[i*3+j] = fmaf(R[i*3+0], S[0*3+j],
                            fmaf(R[i*3+1], S[1*3+j], R[i*3+2]*S[2*3+j]));
        #pragma unroll
        for (int e = 0; e < 9; ++e) R[e] = nR[e];
        lsc += osc;
    }

    if (lane == 0) {
        float r0 = R[0] + R[1] + R[2];
        float r1 = R[3] + R[4] + R[5];
        float r2 = R[6] + R[7] + R[8];
        float p  = fmaf(v0, r0, fmaf(v1, r1, v2 * r2));
        float lp = __logf(p) + lsc;
        if (row_lp) row_lp[b] = lp;
        else        atomicAdd(out_atomic, lp * (1.0f / BATCH));
    }
}

__global__ void reduce_mean(const float* __restrict__ row, float* __restrict__ out)
{
    float s = 0.0f;
    for (int i = threadIdx.x; i < BATCH; i += 1024) s += row[i];
    #pragma unroll
    for (int o = 32; o > 0; o >>= 1) s += __shfl_down(s, o, 64);
    __shared__ float sm[16];
    int w = threadIdx.x >> 6;
    if ((threadIdx.x & 63) == 0) sm[w] = s;
    __syncthreads();
    if (threadIdx.x == 0) {
        float t = 0.0f;
        #pragma unroll
        for (int i = 0; i < 16; ++i) t += sm[i];
        out[0] = t * (1.0f / BATCH);
    }
}

extern "C" void kernel_launch(void* const* d_in, const int* in_sizes, int n_in,
                              void* d_out, int out_size, void* d_ws, size_t ws_size,
                              hipStream_t stream)
{
    const int*   y  = (const int*)d_in[0];
    const float* tp = (const float*)d_in[1];
    const float* ep = (const float*)d_in[2];
    const float* sp = (const float*)d_in[3];
    float* out = (float*)d_out;

    const bool use_ws = (ws_size >= BATCH * sizeof(float));
    if (use_ws) {
        float* row = (float*)d_ws;
        hmm_fwd<<<BATCH/4, 256, 0, stream>>>(y, tp, ep, sp, row, nullptr);
        reduce_mean<<<1, 1024, 0, stream>>>(row, out);
    } else {
        hipMemsetAsync(out, 0, sizeof(float), stream);
        hmm_fwd<<<BATCH/4, 256, 0, stream>>>(y, tp, ep, sp, nullptr, out);
    }
}